// Round 5
// baseline (257.986 us; speedup 1.0000x reference)
//
#include <hip/hip_runtime.h>
#include <hip/hip_bf16.h>

typedef __attribute__((ext_vector_type(8))) __bf16 bf16x8;
typedef __attribute__((ext_vector_type(4))) float f32x4;

#if __has_builtin(__builtin_amdgcn_exp2f)
#define EXP2F(x) __builtin_amdgcn_exp2f(x)
#else
#define EXP2F(x) exp2f(x)
#endif

static constexpr int BB = 8, CC = 64, NN = 4096;
// ws layout (bytes): qfrag[2MB] | kfrag[2MB] | vfrag[4MB]  (total 8MB)
static constexpr size_t QF_OFF = 0;
static constexpr size_t KF_OFF = (size_t)2 << 20;
static constexpr size_t VF_OFF = (size_t)4 << 20;

// Fragment arrays (bf16):
//  qfrag[b][itile(256)][lane][8] : i = itile*16 + (lane&15); qd=lane>>4
//      sections: qd0=qhi, qd1=qlo, qd2=qhi, qd3=qlo   (q pre-scaled by log2e, +bias)
//  kfrag[b][jt(128)][th(2)][lane][8] : j = jt*32 + th*16 + (lane&15)
//      sections: qd0=khi, qd1=khi, qd2=klo, qd3=klo   (+bias)
//  -> energy = (khi+klo)*(qhi+qlo) EXACT over the bf16 pairs (all 4 cross terms)
//  vfrag[b][jt(128)][ct(4)][lane][8] : c = ct*16 + (lane&15); slot r:
//      r<4 -> V[c][jt*32 + 4*qd + r], r>=4 -> V[c][jt*32 + 16 + 4*qd + (r&3)]
//  (jperm matches energy-MFMA C/D layout so exp() results feed PV directly)

__global__ __launch_bounds__(512) void proj_kernel(
    const float* __restrict__ query, const float* __restrict__ value,
    const float* __restrict__ Wq, const float* __restrict__ bq,
    const float* __restrict__ Wk, const float* __restrict__ bk,
    const float* __restrict__ Wv, const float* __restrict__ bv,
    char* __restrict__ ws) {
  __shared__ __bf16 vlds[64][72];   // [px][c], padded row
  __shared__ float  qlds[64][9];    // [px][o], log2e-scaled, +bias
  __shared__ float  klds[64][9];
  const float LOG2E = 1.4426950408889634f;
  int t = threadIdx.x;
  // readfirstlane -> part provably wave-uniform -> weight addrs scalar (s_load)
  int part = __builtin_amdgcn_readfirstlane(t >> 6);   // 0..7
  int px = t & 63;
  int blk = blockIdx.x;
  int b = blk >> 6;
  int px0 = (blk & 63) << 6;        // 64 pixels per block
  size_t inbase = (size_t)b * CC * NN + px0 + px;

  bool isq = part < 4;              // parts 0-3 -> q rows, 4-7 -> k rows
  int qko = (part & 3) * 2;         // two qk output rows per part
  const float* __restrict__ Wqk = isq ? Wq : Wk;

  float vacc[8];
  #pragma unroll
  for (int o = 0; o < 8; ++o) vacc[o] = bv[part * 8 + o];
  float qk0 = 0.f, qk1 = 0.f;

  // chunked over c: 16 q-loads + 16 v-loads in flight, then FMA burst
  #pragma unroll
  for (int cb = 0; cb < 4; ++cb) {
    float xq[16], xv[16];
    #pragma unroll
    for (int cc = 0; cc < 16; ++cc) {
      int c = cb * 16 + cc;
      xq[cc] = query[inbase + (size_t)c * NN];
      xv[cc] = value[inbase + (size_t)c * NN];
    }
    #pragma unroll
    for (int cc = 0; cc < 16; ++cc) {
      int c = cb * 16 + cc;
      qk0 += Wqk[qko * 64 + c] * xq[cc];
      qk1 += Wqk[(qko + 1) * 64 + c] * xq[cc];
      #pragma unroll
      for (int o = 0; o < 8; ++o) vacc[o] += Wv[(part * 8 + o) * 64 + c] * xv[cc];
    }
  }

  #pragma unroll
  for (int o = 0; o < 8; ++o) vlds[px][part * 8 + o] = (__bf16)vacc[o];
  if (isq) {
    qlds[px][qko]     = (qk0 + bq[qko]) * LOG2E;
    qlds[px][qko + 1] = (qk1 + bq[qko + 1]) * LOG2E;
  } else {
    klds[px][qko]     = qk0 + bk[qko];
    klds[px][qko + 1] = qk1 + bk[qko + 1];
  }
  __syncthreads();

  // ---- fragment building (layouts documented above)
  __bf16* qfrag = (__bf16*)(ws + QF_OFF);
  __bf16* kfrag = (__bf16*)(ws + KF_OFF);
  __bf16* vfrag = (__bf16*)(ws + VF_OFF);
  int l = t & 63, cp = l & 15, qd = l >> 4;

  {  // vfrag: all 512 threads, one store each
    int jt = t >> 8, ct = (t >> 6) & 3;
    bf16x8 v8;
    #pragma unroll
    for (int r = 0; r < 8; ++r) {
      int jj = (r < 4) ? (4 * qd + r) : (16 + 4 * qd + (r & 3));
      v8[r] = vlds[jt * 32 + jj][ct * 16 + cp];
    }
    int jtg = (blk & 63) * 2 + jt;
    *(bf16x8*)(vfrag + ((((size_t)b * 128 + jtg) * 4 + ct) * 64 + l) * 8) = v8;
  }
  if (t < 256) {  // kfrag
    int jt = t >> 7, th = (t >> 6) & 1;
    int pxl = jt * 32 + th * 16 + (l & 15);
    bf16x8 k8;
    #pragma unroll
    for (int r = 0; r < 8; ++r) {
      float kv = klds[pxl][r];
      __bf16 hi = (__bf16)kv;
      __bf16 lo = (__bf16)(kv - (float)hi);
      k8[r] = (qd < 2) ? hi : lo;
    }
    int jtg = (blk & 63) * 2 + jt;
    *(bf16x8*)(kfrag + ((((size_t)b * 128 + jtg) * 2 + th) * 64 + l) * 8) = k8;
  } else {  // qfrag
    int it = (t >> 6) & 3;
    int il = it * 16 + (l & 15);
    bf16x8 q8;
    #pragma unroll
    for (int r = 0; r < 8; ++r) {
      float qv = qlds[il][r];
      __bf16 hi = (__bf16)qv;
      __bf16 lo = (__bf16)(qv - (float)hi);
      q8[r] = ((qd & 1) == 0) ? hi : lo;
    }
    int itg = (blk & 63) * 4 + it;
    *(bf16x8*)(qfrag + (((size_t)b * 256 + itg) * 64 + l) * 8) = q8;
  }
}

// Block: 128 i-rows (eight 16-i tiles), 8 waves each take a j-eighth.
// XCD-batch affinity: b = blk & 7 -> all blocks of batch b land on XCD b
// (round-robin dispatch heuristic) -> frag working set 1MB/XCD, L2-resident,
// instead of 8MB thrashing every XCD's 4MB L2 and streaming from L3.
// 128 i-rows per block halves frag L2 traffic vs round-4's 64.
// Even/odd prefetch double-buffer; #pragma unroll 1 keeps body inside I$.
__global__ __launch_bounds__(512, 2) void attn_kernel(
    const char* __restrict__ ws, const float* __restrict__ value,
    float* __restrict__ out) {
  __shared__ float lds_acc[16 * 8 * 64];  // [elem(16)][wave(8)][lane] 32KB, reused 8x
  __shared__ float lds_l[8 * 8 * 64];     // [(it*8+w)][lane] 16KB
  const __bf16* qfrag = (const __bf16*)(ws + QF_OFF);
  const __bf16* kfrag = (const __bf16*)(ws + KF_OFF);
  const __bf16* vfrag = (const __bf16*)(ws + VF_OFF);
  int tid = threadIdx.x;
  int w = tid >> 6, lane = tid & 63;
  int blk = blockIdx.x;            // 256 blocks
  int b = blk & 7;                 // XCD affinity
  int slot = blk >> 3;             // 0..31
  int i0 = slot << 7;
  int itg0 = slot * 8;

  bf16x8 qf[8];
  #pragma unroll
  for (int it = 0; it < 8; ++it)
    qf[it] = *(const bf16x8*)(qfrag + (((size_t)b * 256 + itg0 + it) * 64 + lane) * 8);

  f32x4 acc[4][8];
  #pragma unroll
  for (int ct = 0; ct < 4; ++ct)
    #pragma unroll
    for (int it = 0; it < 8; ++it) acc[ct][it] = (f32x4){0.f, 0.f, 0.f, 0.f};
  float lsum[8] = {0.f, 0.f, 0.f, 0.f, 0.f, 0.f, 0.f, 0.f};

  const __bf16* kb = kfrag + (((size_t)b * 128 + w * 16) * 2 * 64 + lane) * 8;
  const __bf16* vb = vfrag + (((size_t)b * 128 + w * 16) * 4 * 64 + lane) * 8;

  auto compute = [&](bf16x8 kf0, bf16x8 kf1, bf16x8 vf0, bf16x8 vf1,
                     bf16x8 vf2, bf16x8 vf3) {
    const f32x4 z = (f32x4){0.f, 0.f, 0.f, 0.f};
    #pragma unroll
    for (int it = 0; it < 8; ++it) {
      f32x4 e0 = __builtin_amdgcn_mfma_f32_16x16x32_bf16(kf0, qf[it], z, 0, 0, 0);
      f32x4 e1 = __builtin_amdgcn_mfma_f32_16x16x32_bf16(kf1, qf[it], z, 0, 0, 0);
      bf16x8 pf;
      #pragma unroll
      for (int g = 0; g < 4; ++g) {
        float p0 = EXP2F(e0[g]); lsum[it] += p0; pf[g] = (__bf16)p0;
        float p1 = EXP2F(e1[g]); lsum[it] += p1; pf[4 + g] = (__bf16)p1;
      }
      acc[0][it] = __builtin_amdgcn_mfma_f32_16x16x32_bf16(vf0, pf, acc[0][it], 0, 0, 0);
      acc[1][it] = __builtin_amdgcn_mfma_f32_16x16x32_bf16(vf1, pf, acc[1][it], 0, 0, 0);
      acc[2][it] = __builtin_amdgcn_mfma_f32_16x16x32_bf16(vf2, pf, acc[2][it], 0, 0, 0);
      acc[3][it] = __builtin_amdgcn_mfma_f32_16x16x32_bf16(vf3, pf, acc[3][it], 0, 0, 0);
    }
  };

  // prefetch itx=0
  bf16x8 k0a = *(const bf16x8*)(kb);
  bf16x8 k1a = *(const bf16x8*)(kb + 512);
  bf16x8 v0a = *(const bf16x8*)(vb);
  bf16x8 v1a = *(const bf16x8*)(vb + 512);
  bf16x8 v2a = *(const bf16x8*)(vb + 1024);
  bf16x8 v3a = *(const bf16x8*)(vb + 1536);

  #pragma unroll 1
  for (int itx = 0; itx < 8; ++itx) {
    kb += 1024; vb += 2048;
    bf16x8 k0b = *(const bf16x8*)(kb);
    bf16x8 k1b = *(const bf16x8*)(kb + 512);
    bf16x8 v0b = *(const bf16x8*)(vb);
    bf16x8 v1b = *(const bf16x8*)(vb + 512);
    bf16x8 v2b = *(const bf16x8*)(vb + 1024);
    bf16x8 v3b = *(const bf16x8*)(vb + 1536);
    compute(k0a, k1a, v0a, v1a, v2a, v3a);
    kb += 1024; vb += 2048;
    // last prefetch overshoots into ws scratch (256MB) - harmless, never used
    k0a = *(const bf16x8*)(kb);
    k1a = *(const bf16x8*)(kb + 512);
    v0a = *(const bf16x8*)(vb);
    v1a = *(const bf16x8*)(vb + 512);
    v2a = *(const bf16x8*)(vb + 1024);
    v3a = *(const bf16x8*)(vb + 1536);
    compute(k0b, k1b, v0b, v1b, v2b, v3b);
  }

  #pragma unroll
  for (int it = 0; it < 8; ++it) {
    lsum[it] += __shfl_xor(lsum[it], 16, 64);
    lsum[it] += __shfl_xor(lsum[it], 32, 64);
    lds_l[(it * 8 + w) * 64 + lane] = lsum[it];
  }

  // 8-pass epilogue: pass p handles i-tile p (16 elems/wave -> 32KB lds_acc)
  int l = tid & 63;
  #pragma unroll
  for (int p = 0; p < 8; ++p) {
    if (p) __syncthreads();   // protect lds_acc before overwrite
    #pragma unroll
    for (int ct = 0; ct < 4; ++ct)
      #pragma unroll
      for (int r = 0; r < 4; ++r)
        lds_acc[((ct * 4 + r) * 8 + w) * 64 + lane] = acc[ct][p][r];
    __syncthreads();
    float ls = 0.f;
    #pragma unroll
    for (int ww = 0; ww < 8; ++ww) ls += lds_l[(p * 8 + ww) * 64 + (l & 15)];
    float inv = 1.0f / ls;
    int n = i0 + p * 16 + (l & 15);
    #pragma unroll
    for (int r2 = 0; r2 < 2; ++r2) {
      int e = (tid >> 6) * 2 + r2;    // 0..15
      float s = 0.f;
      #pragma unroll
      for (int ww = 0; ww < 8; ++ww) s += lds_acc[(e * 8 + ww) * 64 + l];
      int c = (e >> 2) * 16 + (l >> 4) * 4 + (e & 3);
      size_t idx = ((size_t)b * CC + c) * NN + n;
      out[idx] = s * inv + value[idx];
    }
  }
}

extern "C" void kernel_launch(void* const* d_in, const int* in_sizes, int n_in,
                              void* d_out, int out_size, void* d_ws, size_t ws_size,
                              hipStream_t stream) {
  const float* query = (const float*)d_in[0];
  const float* value = (const float*)d_in[1];
  const float* Wq = (const float*)d_in[2];
  const float* bq = (const float*)d_in[3];
  const float* Wk = (const float*)d_in[4];
  const float* bk = (const float*)d_in[5];
  const float* Wv = (const float*)d_in[6];
  const float* bv = (const float*)d_in[7];
  float* out = (float*)d_out;

  proj_kernel<<<512, 512, 0, stream>>>(query, value, Wq, bq, Wk, bk, Wv, bv, (char*)d_ws);
  // ATTRIBUTION PROBE (round 5): attn is idempotent; dispatching it twice
  // lets the next round's dur_us delta attribute proj vs attn cost exactly.
  attn_kernel<<<256, 512, 0, stream>>>((const char*)d_ws, value, out);
  attn_kernel<<<256, 512, 0, stream>>>((const char*)d_ws, value, out);
}

// Round 6
// 123.987 us; speedup vs baseline: 2.0808x; 2.0808x over previous
//
#include <hip/hip_runtime.h>
#include <hip/hip_bf16.h>

typedef __attribute__((ext_vector_type(8))) __bf16 bf16x8;
typedef __attribute__((ext_vector_type(4))) float f32x4;

#if __has_builtin(__builtin_amdgcn_exp2f)
#define EXP2F(x) __builtin_amdgcn_exp2f(x)
#else
#define EXP2F(x) exp2f(x)
#endif

static constexpr int BB = 8, CC = 64, NN = 4096;
// ws layout (bytes): qfrag[2MB] | kfrag[2MB] | vfrag[4MB]  (total 8MB)
static constexpr size_t QF_OFF = 0;
static constexpr size_t KF_OFF = (size_t)2 << 20;
static constexpr size_t VF_OFF = (size_t)4 << 20;

// Fragment arrays (bf16):
//  qfrag[b][itile(256)][lane][8] : i = itile*16 + (lane&15); qd=lane>>4
//      sections: qd0=qhi, qd1=qlo, qd2=qhi, qd3=qlo   (q pre-scaled by log2e, +bias)
//  kfrag[b][jt(128)][th(2)][lane][8] : j = jt*32 + th*16 + (lane&15)
//      sections: qd0=khi, qd1=khi, qd2=klo, qd3=klo   (+bias)
//  -> energy = (khi+klo)*(qhi+qlo) EXACT over the bf16 pairs (all 4 cross terms)
//  vfrag[b][jt(128)][ct(4)][lane][8] : c = ct*16 + (lane&15); slot r:
//      r<4 -> V[c][jt*32 + 4*qd + r], r>=4 -> V[c][jt*32 + 16 + 4*qd + (r&3)]
//  (jperm matches energy-MFMA C/D layout so exp() results feed PV directly)

__global__ __launch_bounds__(512) void proj_kernel(
    const float* __restrict__ query, const float* __restrict__ value,
    const float* __restrict__ Wq, const float* __restrict__ bq,
    const float* __restrict__ Wk, const float* __restrict__ bk,
    const float* __restrict__ Wv, const float* __restrict__ bv,
    char* __restrict__ ws) {
  __shared__ float qs[64][64];      // staged q-tile [c][px] (16KB)
  __shared__ float vvs[64][64];     // staged v-tile [c][px] (16KB)
  __shared__ __bf16 vlds[64][72];   // [px][c], padded row
  __shared__ float  qlds[64][9];    // [px][o], log2e-scaled, +bias
  __shared__ float  klds[64][9];
  const float LOG2E = 1.4426950408889634f;
  int t = threadIdx.x;
  // readfirstlane -> part provably wave-uniform -> weight addrs scalar (s_load)
  int part = __builtin_amdgcn_readfirstlane(t >> 6);   // 0..7
  int px = t & 63;
  int blk = blockIdx.x;
  int b = blk >> 6;
  int px0 = (blk & 63) << 6;        // 64 pixels per block
  size_t inbase = (size_t)b * CC * NN + px0 + px;

  // ---- cooperative stage: each part loads ITS 8 channels once (coalesced).
  // Round-4 version had every part redundantly load all 64 channels -> 8x
  // global traffic with 16KB-strided lines; that was proj's stall source.
  #pragma unroll
  for (int cc = 0; cc < 8; ++cc) {
    int c = part * 8 + cc;
    qs[c][px]  = query[inbase + (size_t)c * NN];
    vvs[c][px] = value[inbase + (size_t)c * NN];
  }
  __syncthreads();

  bool isq = part < 4;              // parts 0-3 -> q rows, 4-7 -> k rows
  int qko = (part & 3) * 2;         // two qk output rows per part
  const float* __restrict__ Wqk = isq ? Wq : Wk;

  float vacc[8];
  #pragma unroll
  for (int o = 0; o < 8; ++o) vacc[o] = bv[part * 8 + o];
  float qk0 = 0.f, qk1 = 0.f;

  // chunked over c: 16 LDS reads in flight (2 lanes/bank = conflict-free),
  // then FMA burst with scalar (SGPR) weights
  #pragma unroll
  for (int cb = 0; cb < 4; ++cb) {
    float xq[16], xv[16];
    #pragma unroll
    for (int cc = 0; cc < 16; ++cc) {
      xq[cc] = qs[cb * 16 + cc][px];
      xv[cc] = vvs[cb * 16 + cc][px];
    }
    #pragma unroll
    for (int cc = 0; cc < 16; ++cc) {
      int c = cb * 16 + cc;
      qk0 += Wqk[qko * 64 + c] * xq[cc];
      qk1 += Wqk[(qko + 1) * 64 + c] * xq[cc];
      #pragma unroll
      for (int o = 0; o < 8; ++o) vacc[o] += Wv[(part * 8 + o) * 64 + c] * xv[cc];
    }
  }

  #pragma unroll
  for (int o = 0; o < 8; ++o) vlds[px][part * 8 + o] = (__bf16)vacc[o];
  if (isq) {
    qlds[px][qko]     = (qk0 + bq[qko]) * LOG2E;
    qlds[px][qko + 1] = (qk1 + bq[qko + 1]) * LOG2E;
  } else {
    klds[px][qko]     = qk0 + bk[qko];
    klds[px][qko + 1] = qk1 + bk[qko + 1];
  }
  __syncthreads();

  // ---- fragment building (layouts documented above)
  __bf16* qfrag = (__bf16*)(ws + QF_OFF);
  __bf16* kfrag = (__bf16*)(ws + KF_OFF);
  __bf16* vfrag = (__bf16*)(ws + VF_OFF);
  int l = t & 63, cp = l & 15, qd = l >> 4;

  {  // vfrag: all 512 threads, one store each
    int jt = t >> 8, ct = (t >> 6) & 3;
    bf16x8 v8;
    #pragma unroll
    for (int r = 0; r < 8; ++r) {
      int jj = (r < 4) ? (4 * qd + r) : (16 + 4 * qd + (r & 3));
      v8[r] = vlds[jt * 32 + jj][ct * 16 + cp];
    }
    int jtg = (blk & 63) * 2 + jt;
    *(bf16x8*)(vfrag + ((((size_t)b * 128 + jtg) * 4 + ct) * 64 + l) * 8) = v8;
  }
  if (t < 256) {  // kfrag
    int jt = t >> 7, th = (t >> 6) & 1;
    int pxl = jt * 32 + th * 16 + (l & 15);
    bf16x8 k8;
    #pragma unroll
    for (int r = 0; r < 8; ++r) {
      float kv = klds[pxl][r];
      __bf16 hi = (__bf16)kv;
      __bf16 lo = (__bf16)(kv - (float)hi);
      k8[r] = (qd < 2) ? hi : lo;
    }
    int jtg = (blk & 63) * 2 + jt;
    *(bf16x8*)(kfrag + ((((size_t)b * 128 + jtg) * 2 + th) * 64 + l) * 8) = k8;
  } else {  // qfrag
    int it = (t >> 6) & 3;
    int il = it * 16 + (l & 15);
    bf16x8 q8;
    #pragma unroll
    for (int r = 0; r < 8; ++r) {
      float qv = qlds[il][r];
      __bf16 hi = (__bf16)qv;
      __bf16 lo = (__bf16)(qv - (float)hi);
      q8[r] = ((qd & 1) == 0) ? hi : lo;
    }
    int itg = (blk & 63) * 4 + it;
    *(bf16x8*)(qfrag + (((size_t)b * 256 + itg) * 64 + l) * 8) = q8;
  }
}

// Block: 64 i-rows (four 16-i tiles), 4 waves each take a j-quarter.
// Non-spilling tile: acc[4][4]=64 AGPR + qf[4]=16 + 2x6 prefetch regs fits the
// (256,2) budget of 256 unified regs (round-5 lesson: AGPRs count against it).
// XCD-batch affinity: b = blk&7 -> round-robin dispatch puts all of batch b's
// blocks on XCD b; per-XCD frag working set 1.25MB -> L2-resident.
// Even/odd register prefetch hides frag L2 latency; unroll 1 keeps I$ happy.
__global__ __launch_bounds__(256, 2) void attn_kernel(
    const char* __restrict__ ws, const float* __restrict__ value,
    float* __restrict__ out) {
  __shared__ float lds_acc[32 * 4 * 64];  // [elem(32)][wave(4)][lane] 32KB, reused 2x
  __shared__ float lds_l[16 * 64];        // [(it*4+w)][lane]
  const __bf16* qfrag = (const __bf16*)(ws + QF_OFF);
  const __bf16* kfrag = (const __bf16*)(ws + KF_OFF);
  const __bf16* vfrag = (const __bf16*)(ws + VF_OFF);
  int tid = threadIdx.x;
  int w = tid >> 6, lane = tid & 63;
  int blk = blockIdx.x;            // 512 blocks
  int b = blk & 7;                 // XCD affinity
  int slot = blk >> 3;             // 0..63
  int i0 = slot << 6;
  int itg0 = slot * 4;

  bf16x8 qf[4];
  #pragma unroll
  for (int it = 0; it < 4; ++it)
    qf[it] = *(const bf16x8*)(qfrag + (((size_t)b * 256 + itg0 + it) * 64 + lane) * 8);

  f32x4 acc[4][4];
  #pragma unroll
  for (int ct = 0; ct < 4; ++ct)
    #pragma unroll
    for (int it = 0; it < 4; ++it) acc[ct][it] = (f32x4){0.f, 0.f, 0.f, 0.f};
  float lsum[4] = {0.f, 0.f, 0.f, 0.f};

  const __bf16* kb = kfrag + (((size_t)b * 128 + w * 32) * 2 * 64 + lane) * 8;
  const __bf16* vb = vfrag + (((size_t)b * 128 + w * 32) * 4 * 64 + lane) * 8;

  auto compute = [&](bf16x8 kf0, bf16x8 kf1, bf16x8 vf0, bf16x8 vf1,
                     bf16x8 vf2, bf16x8 vf3) {
    const f32x4 z = (f32x4){0.f, 0.f, 0.f, 0.f};
    #pragma unroll
    for (int it = 0; it < 4; ++it) {
      f32x4 e0 = __builtin_amdgcn_mfma_f32_16x16x32_bf16(kf0, qf[it], z, 0, 0, 0);
      f32x4 e1 = __builtin_amdgcn_mfma_f32_16x16x32_bf16(kf1, qf[it], z, 0, 0, 0);
      bf16x8 pf;
      #pragma unroll
      for (int g = 0; g < 4; ++g) {
        float p0 = EXP2F(e0[g]); lsum[it] += p0; pf[g] = (__bf16)p0;
        float p1 = EXP2F(e1[g]); lsum[it] += p1; pf[4 + g] = (__bf16)p1;
      }
      acc[0][it] = __builtin_amdgcn_mfma_f32_16x16x32_bf16(vf0, pf, acc[0][it], 0, 0, 0);
      acc[1][it] = __builtin_amdgcn_mfma_f32_16x16x32_bf16(vf1, pf, acc[1][it], 0, 0, 0);
      acc[2][it] = __builtin_amdgcn_mfma_f32_16x16x32_bf16(vf2, pf, acc[2][it], 0, 0, 0);
      acc[3][it] = __builtin_amdgcn_mfma_f32_16x16x32_bf16(vf3, pf, acc[3][it], 0, 0, 0);
    }
  };

  // prefetch itx=0
  bf16x8 k0a = *(const bf16x8*)(kb);
  bf16x8 k1a = *(const bf16x8*)(kb + 512);
  bf16x8 v0a = *(const bf16x8*)(vb);
  bf16x8 v1a = *(const bf16x8*)(vb + 512);
  bf16x8 v2a = *(const bf16x8*)(vb + 1024);
  bf16x8 v3a = *(const bf16x8*)(vb + 1536);

  #pragma unroll 1
  for (int itx = 0; itx < 16; ++itx) {
    kb += 1024; vb += 2048;
    bf16x8 k0b = *(const bf16x8*)(kb);
    bf16x8 k1b = *(const bf16x8*)(kb + 512);
    bf16x8 v0b = *(const bf16x8*)(vb);
    bf16x8 v1b = *(const bf16x8*)(vb + 512);
    bf16x8 v2b = *(const bf16x8*)(vb + 1024);
    bf16x8 v3b = *(const bf16x8*)(vb + 1536);
    compute(k0a, k1a, v0a, v1a, v2a, v3a);
    kb += 1024; vb += 2048;
    // last prefetch overshoots into ws scratch (256MB) - harmless, never used
    k0a = *(const bf16x8*)(kb);
    k1a = *(const bf16x8*)(kb + 512);
    v0a = *(const bf16x8*)(vb);
    v1a = *(const bf16x8*)(vb + 512);
    v2a = *(const bf16x8*)(vb + 1024);
    v3a = *(const bf16x8*)(vb + 1536);
    compute(k0b, k1b, v0b, v1b, v2b, v3b);
  }

  #pragma unroll
  for (int it = 0; it < 4; ++it) {
    lsum[it] += __shfl_xor(lsum[it], 16, 64);
    lsum[it] += __shfl_xor(lsum[it], 32, 64);
    lds_l[(it * 4 + w) * 64 + lane] = lsum[it];
  }

  int ect = tid >> 6, l = tid & 63;
  #pragma unroll
  for (int p = 0; p < 2; ++p) {
    if (p) __syncthreads();   // protect lds_acc from overwrite before reads done
    #pragma unroll
    for (int ct = 0; ct < 4; ++ct)
      #pragma unroll
      for (int itl = 0; itl < 2; ++itl)
        #pragma unroll
        for (int r = 0; r < 4; ++r) {
          int e = ct * 8 + itl * 4 + r;
          lds_acc[(e * 4 + w) * 64 + lane] = acc[ct][2 * p + itl][r];
        }
    __syncthreads();
    #pragma unroll
    for (int itl = 0; itl < 2; ++itl) {
      int it = 2 * p + itl;
      float ls = 0.f;
      #pragma unroll
      for (int ww = 0; ww < 4; ++ww) ls += lds_l[(it * 4 + ww) * 64 + (l & 15)];
      float inv = 1.0f / ls;
      int n = i0 + it * 16 + (l & 15);
      #pragma unroll
      for (int r = 0; r < 4; ++r) {
        int e = ect * 8 + itl * 4 + r;
        float s = 0.f;
        #pragma unroll
        for (int ww = 0; ww < 4; ++ww) s += lds_acc[(e * 4 + ww) * 64 + l];
        int c = ect * 16 + (l >> 4) * 4 + r;
        size_t idx = ((size_t)b * CC + c) * NN + n;
        out[idx] = s * inv + value[idx];
      }
    }
  }
}

extern "C" void kernel_launch(void* const* d_in, const int* in_sizes, int n_in,
                              void* d_out, int out_size, void* d_ws, size_t ws_size,
                              hipStream_t stream) {
  const float* query = (const float*)d_in[0];
  const float* value = (const float*)d_in[1];
  const float* Wq = (const float*)d_in[2];
  const float* bq = (const float*)d_in[3];
  const float* Wk = (const float*)d_in[4];
  const float* bk = (const float*)d_in[5];
  const float* Wv = (const float*)d_in[6];
  const float* bv = (const float*)d_in[7];
  float* out = (float*)d_out;

  proj_kernel<<<512, 512, 0, stream>>>(query, value, Wq, bq, Wk, bk, Wv, bv, (char*)d_ws);
  attn_kernel<<<512, 256, 0, stream>>>((const char*)d_ws, value, out);
}